// Round 1
// baseline (388.735 us; speedup 1.0000x reference)
//
#include <hip/hip_runtime.h>
#include <math.h>

typedef short  s16x8 __attribute__((ext_vector_type(8)));
typedef float  f32x4 __attribute__((ext_vector_type(4)));
typedef float  f32x2 __attribute__((ext_vector_type(2)));

#define LN_EPS 1e-6f

__device__ __forceinline__ unsigned short f2bf(float x) {
  union { float f; unsigned u; } v; v.f = x;
  unsigned r = v.u + 0x7FFFu + ((v.u >> 16) & 1u);  // RNE
  return (unsigned short)(r >> 16);
}
__device__ __forceinline__ float bf2f(unsigned short u) {
  union { unsigned u; float f; } v; v.u = ((unsigned)u) << 16;
  return v.f;
}
__device__ __forceinline__ float sigmoidf_(float x) { return 1.0f / (1.0f + expf(-x)); }

__device__ __forceinline__ float wredsum(float v) {
  #pragma unroll
  for (int m = 32; m >= 1; m >>= 1) v += __shfl_xor(v, m);
  return v;
}

__device__ __forceinline__ f32x4 mfma16(s16x8 a, s16x8 b, f32x4 c) {
  return __builtin_amdgcn_mfma_f32_16x16x32_bf16(a, b, c, 0, 0, 0);
}

// stage rows x 256 f32 -> bf16 into XOR-swizzled LDS ([row][k], byte ^= (row&7)<<4)
__device__ __forceinline__ void stage_rows(unsigned short* A, const float* src,
                                           int validrows, int totrows,
                                           int tid, int nthreads) {
  char* Ab = (char*)A;
  int npairs = totrows * 128;
  for (int p = tid; p < npairs; p += nthreads) {
    int row = p >> 7, kp = p & 127;
    unsigned u = 0u;
    if (row < validrows) {
      f32x2 v = *(const f32x2*)(src + row * 256 + kp * 2);
      u = (unsigned)f2bf(v.x) | ((unsigned)f2bf(v.y) << 16);
    }
    int byte = row * 512 + ((kp * 4) ^ ((row & 7) << 4));
    *(unsigned*)(Ab + byte) = u;
  }
}

// A-frag: lane holds A[row][kk*32 + 8*hi + j], j=0..7
__device__ __forceinline__ s16x8 readA(const unsigned short* A, int row, int kk, int hi) {
  const char* Ab = (const char*)A;
  int byte = row * 512 + (((kk * 64) + hi * 16) ^ ((row & 7) << 4));
  return *(const s16x8*)(Ab + byte);
}
// B-frag from transposed bf16 weights Bt[N][256]: lane holds B[kk*32+8*hi+j][col]
__device__ __forceinline__ s16x8 readB(const unsigned short* Bt, int col, int kk, int hi) {
  return *(const s16x8*)(Bt + col * 256 + kk * 32 + hi * 8);
}

// ---------------- K0: weight convert + transpose to bf16 ----------------
__global__ __launch_bounds__(256) void k_convw(
    const float* Win, const float* Wq, const float* Whid, const float* Wctx, const float* Wenc,
    unsigned short* bt_in, unsigned short* bt_q, unsigned short* bt_hid,
    unsigned short* bt_ctx, unsigned short* bt_enc) {
  int e = blockIdx.x * 256 + threadIdx.x;
  if (e < 196608) {  // W_in [256][768] -> bt_in [768][256]
    int k = e & 255, n = e >> 8;
    bt_in[n * 256 + k] = f2bf(Win[k * 768 + n]);
    return;
  }
  e -= 196608;
  int m = e >> 16;          // 0..3
  int r = e & 65535;
  int k = r & 255, n = r >> 8;
  const float* src = (m == 0) ? Wq : (m == 1) ? Whid : (m == 2) ? Wctx : Wenc;
  unsigned short* dst = (m == 0) ? bt_q : (m == 1) ? bt_hid : (m == 2) ? bt_ctx : bt_enc;
  dst[n * 256 + k] = f2bf(src[k * 256 + n]);
}

// ---------------- K1: preact = LN(prev @ W_in) -> z,hg,xt ----------------
__global__ __launch_bounds__(256) void k_preact(
    const float* prev, const unsigned short* bt_in,
    const float* g_pre, const float* b_pre,
    float* Z, float* HG, float* XT) {
  __shared__ __align__(16) unsigned short A[16 * 256];
  __shared__ float C[16 * 768];
  int tid = threadIdx.x, lane = tid & 63, wave = tid >> 6;
  int hi = lane >> 4, lo = lane & 15;
  int r0 = blockIdx.x * 16;
  stage_rows(A, prev + (size_t)r0 * 256, 16, 16, tid, 256);
  __syncthreads();
  f32x4 acc[12];
  #pragma unroll
  for (int ct = 0; ct < 12; ct++) acc[ct] = f32x4{0.f, 0.f, 0.f, 0.f};
  #pragma unroll
  for (int kk = 0; kk < 8; kk++) {
    s16x8 a = readA(A, lo, kk, hi);
    #pragma unroll
    for (int ct = 0; ct < 12; ct++) {
      s16x8 b = readB(bt_in, wave * 192 + ct * 16 + lo, kk, hi);
      acc[ct] = mfma16(a, b, acc[ct]);
    }
  }
  #pragma unroll
  for (int ct = 0; ct < 12; ct++) {
    int col = wave * 192 + ct * 16 + lo;
    #pragma unroll
    for (int r = 0; r < 4; r++) C[(hi * 4 + r) * 768 + col] = acc[ct][r];
  }
  __syncthreads();
  #pragma unroll
  for (int mm = 0; mm < 4; mm++) {
    int m = wave * 4 + mm;
    float x[12]; float s = 0.f, q = 0.f;
    #pragma unroll
    for (int i = 0; i < 12; i++) {
      x[i] = C[m * 768 + lane + 64 * i];
      s += x[i]; q += x[i] * x[i];
    }
    s = wredsum(s); q = wredsum(q);
    float mean = s * (1.0f / 768.0f);
    float var = q * (1.0f / 768.0f) - mean * mean;
    float rstd = rsqrtf(var + LN_EPS);
    int gr = r0 + m;
    #pragma unroll
    for (int i = 0; i < 12; i++) {
      int c = lane + 64 * i;
      float y = g_pre[c] * (x[i] - mean) * rstd + b_pre[c];
      if (c < 256)      Z [gr * 256 + c]         = sigmoidf_(y);
      else if (c < 512) HG[gr * 256 + (c - 256)] = sigmoidf_(y);
      else              XT[gr * 256 + (c - 512)] = y;
    }
  }
}

// ---------------- K2: SRU scan over T ----------------
__global__ __launch_bounds__(256) void k_scan(
    const float* hidden, const float* Z, const float* XT,
    float* SS, float* outFinalH) {
  int tid = blockIdx.x * 256 + threadIdx.x;  // 0..8191 == b*256+d
  float h = hidden[tid];
  for (int t0 = 0; t0 < 128; t0 += 8) {
    float zc[8], xc[8];
    #pragma unroll
    for (int j = 0; j < 8; j++) {
      zc[j] = Z [(t0 + j) * 8192 + tid];
      xc[j] = XT[(t0 + j) * 8192 + tid];
    }
    #pragma unroll
    for (int j = 0; j < 8; j++) {
      h = (1.0f - zc[j]) * h + zc[j] * xc[j];
      SS[(t0 + j) * 8192 + tid] = h;
    }
  }
  outFinalH[tid] = h;
}

// ---------------- K3: q = LN(ss @ W_q) ----------------
__global__ __launch_bounds__(256) void k_qproj(
    const float* SS, const unsigned short* bt_q,
    const float* g_q, const float* b_q, float* Q) {
  __shared__ __align__(16) unsigned short A[16 * 256];
  __shared__ float C[16 * 256];
  int tid = threadIdx.x, lane = tid & 63, wave = tid >> 6;
  int hi = lane >> 4, lo = lane & 15;
  int r0 = blockIdx.x * 16;
  stage_rows(A, SS + (size_t)r0 * 256, 16, 16, tid, 256);
  __syncthreads();
  f32x4 acc[4];
  #pragma unroll
  for (int ct = 0; ct < 4; ct++) acc[ct] = f32x4{0.f, 0.f, 0.f, 0.f};
  #pragma unroll
  for (int kk = 0; kk < 8; kk++) {
    s16x8 a = readA(A, lo, kk, hi);
    #pragma unroll
    for (int ct = 0; ct < 4; ct++) {
      s16x8 b = readB(bt_q, wave * 64 + ct * 16 + lo, kk, hi);
      acc[ct] = mfma16(a, b, acc[ct]);
    }
  }
  #pragma unroll
  for (int ct = 0; ct < 4; ct++) {
    int col = wave * 64 + ct * 16 + lo;
    #pragma unroll
    for (int r = 0; r < 4; r++) C[(hi * 4 + r) * 256 + col] = acc[ct][r];
  }
  __syncthreads();
  #pragma unroll
  for (int mm = 0; mm < 4; mm++) {
    int m = wave * 4 + mm;
    float x[4]; float s = 0.f, q = 0.f;
    #pragma unroll
    for (int i = 0; i < 4; i++) {
      x[i] = C[m * 256 + lane + 64 * i];
      s += x[i]; q += x[i] * x[i];
    }
    s = wredsum(s); q = wredsum(q);
    float mean = s * (1.0f / 256.0f);
    float var = q * (1.0f / 256.0f) - mean * mean;
    float rstd = rsqrtf(var + LN_EPS);
    int gr = r0 + m;
    #pragma unroll
    for (int i = 0; i < 4; i++) {
      int c = lane + 64 * i;
      Q[gr * 256 + c] = g_q[c] * (x[i] - mean) * rstd + b_q[c];
    }
  }
}

// ---------------- K4: fused pctx GEMM + LN + MLP-attention ----------------
__global__ __launch_bounds__(512) void k_attn(
    const float* enc, const unsigned short* bt_enc, const float* Q,
    const float* g_enc, const float* b_enc, const float* v_att,
    float* AOUT, float* attnOut) {
  // AP is unioned: swizzled A staging during GEMM, then linear bf16 P tile.
  __shared__ __align__(16) unsigned short AP[112 * 256];  // 57344 B
  __shared__ float scores[112];
  __shared__ float probs[112];
  __shared__ float qs[256], gs[256], bs[256], vs[256];
  int n = blockIdx.x;
  int tid = threadIdx.x, lane = tid & 63, wave = tid >> 6;
  int hi = lane >> 4, lo = lane & 15;
  if (tid < 256) {
    qs[tid] = Q[n * 256 + tid];
    gs[tid] = g_enc[tid]; bs[tid] = b_enc[tid]; vs[tid] = v_att[tid];
  }
  stage_rows(AP, enc + (size_t)n * 25600, 100, 112, tid, 512);
  __syncthreads();
  f32x4 acc[7][2];
  #pragma unroll
  for (int mt = 0; mt < 7; mt++) {
    acc[mt][0] = f32x4{0.f, 0.f, 0.f, 0.f};
    acc[mt][1] = f32x4{0.f, 0.f, 0.f, 0.f};
  }
  #pragma unroll
  for (int kk = 0; kk < 8; kk++) {
    s16x8 b0 = readB(bt_enc, wave * 32 + lo, kk, hi);
    s16x8 b1 = readB(bt_enc, wave * 32 + 16 + lo, kk, hi);
    #pragma unroll
    for (int mt = 0; mt < 7; mt++) {
      s16x8 a = readA(AP, mt * 16 + lo, kk, hi);
      acc[mt][0] = mfma16(a, b0, acc[mt][0]);
      acc[mt][1] = mfma16(a, b1, acc[mt][1]);
    }
  }
  __syncthreads();   // A reads done; AP becomes the P tile
  #pragma unroll
  for (int mt = 0; mt < 7; mt++) {
    #pragma unroll
    for (int ct = 0; ct < 2; ct++) {
      int col = wave * 32 + ct * 16 + lo;
      #pragma unroll
      for (int r = 0; r < 4; r++) {
        int row = mt * 16 + hi * 4 + r;
        if (row < 100) AP[row * 256 + col] = f2bf(acc[mt][ct][r]);
      }
    }
  }
  __syncthreads();
  // LN + scores per row
  for (int m = wave; m < 100; m += 8) {
    float x[4]; float s = 0.f, q = 0.f;
    #pragma unroll
    for (int i = 0; i < 4; i++) {
      x[i] = bf2f(AP[m * 256 + lane + 64 * i]);
      s += x[i]; q += x[i] * x[i];
    }
    s = wredsum(s); q = wredsum(q);
    float mean = s * (1.0f / 256.0f);
    float var = q * (1.0f / 256.0f) - mean * mean;
    float rstd = rsqrtf(var + LN_EPS);
    float sc = 0.f;
    #pragma unroll
    for (int i = 0; i < 4; i++) {
      int c = lane + 64 * i;
      float y = gs[c] * (x[i] - mean) * rstd + bs[c];
      AP[m * 256 + c] = f2bf(y);
      sc += vs[c] * tanhf(qs[c] + y);
    }
    sc = wredsum(sc);
    if (lane == 0) scores[m] = sc;
  }
  __syncthreads();
  if (wave == 0) {
    float s1 = (lane < 100) ? scores[lane] : -INFINITY;
    float s2 = (lane + 64 < 100) ? scores[lane + 64] : -INFINITY;
    float mx = fmaxf(s1, s2);
    #pragma unroll
    for (int m = 32; m >= 1; m >>= 1) mx = fmaxf(mx, __shfl_xor(mx, m));
    float e1 = (lane < 100) ? expf(s1 - mx) : 0.f;
    float e2 = (lane + 64 < 100) ? expf(s2 - mx) : 0.f;
    float sm = wredsum(e1 + e2);
    float inv = 1.0f / sm;
    probs[lane] = e1 * inv;
    if (lane + 64 < 112) probs[lane + 64] = e2 * inv;
    if (lane < 100) attnOut[(size_t)n * 100 + lane] = e1 * inv;
    if (lane + 64 < 100) attnOut[(size_t)n * 100 + lane + 64] = e2 * inv;
  }
  __syncthreads();
  if (tid < 256) {
    float a = 0.f;
    for (int s = 0; s < 100; s++) a += probs[s] * bf2f(AP[s * 256 + tid]);
    AOUT[(size_t)n * 256 + tid] = a * 0.0625f;  // / sqrt(256)
  }
}

// ---------------- K5: out = highway(tanh(LN(ss@W_hid)+LN(aout@W_ctx))) ----------------
__global__ __launch_bounds__(256) void k_out(
    const float* SS, const float* AOUT,
    const unsigned short* bt_hid, const unsigned short* bt_ctx,
    const float* g_h, const float* b_h, const float* g_c, const float* b_c,
    const float* HG, const float* prev, float* out) {
  __shared__ __align__(16) unsigned short A1[16 * 256];
  __shared__ __align__(16) unsigned short A2[16 * 256];
  __shared__ float C1[16 * 256];
  __shared__ float C2[16 * 256];
  int tid = threadIdx.x, lane = tid & 63, wave = tid >> 6;
  int hi = lane >> 4, lo = lane & 15;
  int r0 = blockIdx.x * 16;
  stage_rows(A1, SS + (size_t)r0 * 256, 16, 16, tid, 256);
  stage_rows(A2, AOUT + (size_t)r0 * 256, 16, 16, tid, 256);
  __syncthreads();
  f32x4 acc1[4], acc2[4];
  #pragma unroll
  for (int ct = 0; ct < 4; ct++) {
    acc1[ct] = f32x4{0.f, 0.f, 0.f, 0.f};
    acc2[ct] = f32x4{0.f, 0.f, 0.f, 0.f};
  }
  #pragma unroll
  for (int kk = 0; kk < 8; kk++) {
    s16x8 a1 = readA(A1, lo, kk, hi);
    s16x8 a2 = readA(A2, lo, kk, hi);
    #pragma unroll
    for (int ct = 0; ct < 4; ct++) {
      int col = wave * 64 + ct * 16 + lo;
      s16x8 b1 = readB(bt_hid, col, kk, hi);
      s16x8 b2 = readB(bt_ctx, col, kk, hi);
      acc1[ct] = mfma16(a1, b1, acc1[ct]);
      acc2[ct] = mfma16(a2, b2, acc2[ct]);
    }
  }
  #pragma unroll
  for (int ct = 0; ct < 4; ct++) {
    int col = wave * 64 + ct * 16 + lo;
    #pragma unroll
    for (int r = 0; r < 4; r++) {
      C1[(hi * 4 + r) * 256 + col] = acc1[ct][r];
      C2[(hi * 4 + r) * 256 + col] = acc2[ct][r];
    }
  }
  __syncthreads();
  #pragma unroll
  for (int mm = 0; mm < 4; mm++) {
    int m = wave * 4 + mm;
    float x1[4], x2[4];
    float s1 = 0.f, q1 = 0.f, s2 = 0.f, q2 = 0.f;
    #pragma unroll
    for (int i = 0; i < 4; i++) {
      x1[i] = C1[m * 256 + lane + 64 * i];
      x2[i] = C2[m * 256 + lane + 64 * i];
      s1 += x1[i]; q1 += x1[i] * x1[i];
      s2 += x2[i]; q2 += x2[i] * x2[i];
    }
    s1 = wredsum(s1); q1 = wredsum(q1);
    s2 = wredsum(s2); q2 = wredsum(q2);
    float mean1 = s1 * (1.0f / 256.0f), var1 = q1 * (1.0f / 256.0f) - mean1 * mean1;
    float mean2 = s2 * (1.0f / 256.0f), var2 = q2 * (1.0f / 256.0f) - mean2 * mean2;
    float rstd1 = rsqrtf(var1 + LN_EPS), rstd2 = rsqrtf(var2 + LN_EPS);
    int gr = r0 + m;
    #pragma unroll
    for (int i = 0; i < 4; i++) {
      int c = lane + 64 * i;
      float y1 = g_h[c] * (x1[i] - mean1) * rstd1 + b_h[c];
      float y2 = g_c[c] * (x2[i] - mean2) * rstd2 + b_c[c];
      float y = tanhf(y1 + y2);
      float g = HG[gr * 256 + c];
      float pv = prev[gr * 256 + c];
      out[gr * 256 + c] = (1.0f - g) * y + g * pv;
    }
  }
}

extern "C" void kernel_launch(void* const* d_in, const int* in_sizes, int n_in,
                              void* d_out, int out_size, void* d_ws, size_t ws_size,
                              hipStream_t stream) {
  const float* prev   = (const float*)d_in[0];
  const float* hidden = (const float*)d_in[1];
  const float* enc    = (const float*)d_in[2];
  const float* W_in   = (const float*)d_in[3];
  const float* W_hid  = (const float*)d_in[4];
  const float* W_ctx  = (const float*)d_in[5];
  const float* W_enc  = (const float*)d_in[6];
  const float* W_q    = (const float*)d_in[7];
  const float* v_att  = (const float*)d_in[8];
  const float* g_pre  = (const float*)d_in[9];
  const float* b_pre  = (const float*)d_in[10];
  const float* g_enc  = (const float*)d_in[11];
  const float* b_enc  = (const float*)d_in[12];
  const float* g_h    = (const float*)d_in[13];
  const float* b_h    = (const float*)d_in[14];
  const float* g_c    = (const float*)d_in[15];
  const float* b_c    = (const float*)d_in[16];
  const float* g_q    = (const float*)d_in[17];
  const float* b_q    = (const float*)d_in[18];

  char* ws = (char*)d_ws;
  unsigned short* BT_IN  = (unsigned short*)(ws + 0);        // 768x256 bf16
  unsigned short* BT_Q   = (unsigned short*)(ws + 393216);   // 256x256 bf16 (transposed)
  unsigned short* BT_HID = (unsigned short*)(ws + 524288);
  unsigned short* BT_CTX = (unsigned short*)(ws + 655360);
  unsigned short* BT_ENC = (unsigned short*)(ws + 786432);
  float* Z    = (float*)(ws + 917504);    // [4096][256]
  float* HG   = (float*)(ws + 5111808);
  float* XT   = (float*)(ws + 9306112);
  float* SS   = (float*)(ws + 13500416);
  float* Q    = (float*)(ws + 17694720);
  float* AOUT = (float*)(ws + 21889024);

  float* out    = (float*)d_out;          // [4096][256]
  float* finalH = out + 1048576;          // [32][256]
  float* attnO  = out + 1056768;          // [4096][100]

  k_convw <<<1792, 256, 0, stream>>>(W_in, W_q, W_hid, W_ctx, W_enc,
                                     BT_IN, BT_Q, BT_HID, BT_CTX, BT_ENC);
  k_preact<<<256, 256, 0, stream>>>(prev, BT_IN, g_pre, b_pre, Z, HG, XT);
  k_scan  <<<32, 256, 0, stream>>>(hidden, Z, XT, SS, finalH);
  k_qproj <<<256, 256, 0, stream>>>(SS, BT_Q, g_q, b_q, Q);
  k_attn  <<<4096, 512, 0, stream>>>(enc, BT_ENC, Q, g_enc, b_enc, v_att, AOUT, attnO);
  k_out   <<<256, 256, 0, stream>>>(SS, AOUT, BT_HID, BT_CTX,
                                    g_h, b_h, g_c, b_c, HG, prev, out);
}

// Round 2
// 307.680 us; speedup vs baseline: 1.2634x; 1.2634x over previous
//
#include <hip/hip_runtime.h>
#include <hip/hip_bf16.h>
#include <math.h>

typedef short  s16x8 __attribute__((ext_vector_type(8)));
typedef float  f32x4 __attribute__((ext_vector_type(4)));
typedef float  f32x2 __attribute__((ext_vector_type(2)));

#define LN_EPS 1e-6f

__device__ __forceinline__ unsigned short f2bf(float x) {
  union { float f; unsigned u; } v; v.f = x;
  unsigned r = v.u + 0x7FFFu + ((v.u >> 16) & 1u);  // RNE
  return (unsigned short)(r >> 16);
}
__device__ __forceinline__ float bf2f(unsigned short u) {
  union { unsigned u; float f; } v; v.u = ((unsigned)u) << 16;
  return v.f;
}
__device__ __forceinline__ float bflo(unsigned u) {
  union { unsigned u; float f; } v; v.u = u << 16; return v.f;
}
__device__ __forceinline__ float bfhi(unsigned u) {
  union { unsigned u; float f; } v; v.u = u & 0xFFFF0000u; return v.f;
}
__device__ __forceinline__ unsigned pack_bf2(float a, float b) {
  __hip_bfloat162 h = __float22bfloat162_rn(make_float2(a, b));
  unsigned u; __builtin_memcpy(&u, &h, 4); return u;
}
// fast tanh: 1 - 2/(e^{2x}+1); saturates correctly (exp->inf => 1, exp->0 => -1)
__device__ __forceinline__ float fast_tanh(float x) {
  float e = __expf(2.0f * x);
  return 1.0f - 2.0f * __builtin_amdgcn_rcpf(e + 1.0f);
}
__device__ __forceinline__ float fast_sigmoid(float x) {
  return __builtin_amdgcn_rcpf(1.0f + __expf(-x));
}

__device__ __forceinline__ float wredsum(float v) {
  #pragma unroll
  for (int m = 32; m >= 1; m >>= 1) v += __shfl_xor(v, m);
  return v;
}

__device__ __forceinline__ f32x4 mfma16(s16x8 a, s16x8 b, f32x4 c) {
  return __builtin_amdgcn_mfma_f32_16x16x32_bf16(a, b, c, 0, 0, 0);
}

// stage rows x 256 f32 -> bf16 into XOR-swizzled LDS ([row][k], byte ^= (row&7)<<4)
// f32x4 loads, packed cvt, 8B LDS writes.
__device__ __forceinline__ void stage_rows(unsigned short* A, const float* src,
                                           int rows, int tid, int nthreads) {
  char* Ab = (char*)A;
  int nquads = rows * 64;
  for (int p = tid; p < nquads; p += nthreads) {
    int row = p >> 6, kq = p & 63;
    f32x4 v = *(const f32x4*)(src + row * 256 + kq * 4);
    unsigned u0 = pack_bf2(v.x, v.y);
    unsigned u1 = pack_bf2(v.z, v.w);
    int byte = row * 512 + ((kq * 8) ^ ((row & 7) << 4));
    *(uint2*)(Ab + byte) = uint2{u0, u1};
  }
}

// A-frag: lane holds A[row][kk*32 + 8*hi + j], j=0..7
__device__ __forceinline__ s16x8 readA(const unsigned short* A, int row, int kk, int hi) {
  const char* Ab = (const char*)A;
  int byte = row * 512 + (((kk * 64) + hi * 16) ^ ((row & 7) << 4));
  return *(const s16x8*)(Ab + byte);
}
// B-frag from transposed bf16 weights Bt[N][256]: lane holds B[kk*32+8*hi+j][col]
__device__ __forceinline__ s16x8 readB(const unsigned short* Bt, int col, int kk, int hi) {
  return *(const s16x8*)(Bt + col * 256 + kk * 32 + hi * 8);
}

// ---------------- K0: weight convert + transpose to bf16 ----------------
__global__ __launch_bounds__(256) void k_convw(
    const float* Win, const float* Wq, const float* Whid, const float* Wctx, const float* Wenc,
    unsigned short* bt_in, unsigned short* bt_q, unsigned short* bt_hid,
    unsigned short* bt_ctx, unsigned short* bt_enc) {
  int e = blockIdx.x * 256 + threadIdx.x;
  if (e < 196608) {  // W_in [256][768] -> bt_in [768][256]
    int k = e & 255, n = e >> 8;
    bt_in[n * 256 + k] = f2bf(Win[k * 768 + n]);
    return;
  }
  e -= 196608;
  int m = e >> 16;          // 0..3
  int r = e & 65535;
  int k = r & 255, n = r >> 8;
  const float* src = (m == 0) ? Wq : (m == 1) ? Whid : (m == 2) ? Wctx : Wenc;
  unsigned short* dst = (m == 0) ? bt_q : (m == 1) ? bt_hid : (m == 2) ? bt_ctx : bt_enc;
  dst[n * 256 + k] = f2bf(src[k * 256 + n]);
}

// ---------------- K1: preact = LN(prev @ W_in) -> z,hg,xt ----------------
__global__ __launch_bounds__(256) void k_preact(
    const float* prev, const unsigned short* bt_in,
    const float* g_pre, const float* b_pre,
    float* Z, float* HG, float* XT) {
  __shared__ __align__(16) unsigned short A[16 * 256];
  __shared__ float C[16 * 768];
  int tid = threadIdx.x, lane = tid & 63, wave = tid >> 6;
  int hi = lane >> 4, lo = lane & 15;
  int r0 = blockIdx.x * 16;
  stage_rows(A, prev + (size_t)r0 * 256, 16, tid, 256);
  __syncthreads();
  f32x4 acc[12];
  #pragma unroll
  for (int ct = 0; ct < 12; ct++) acc[ct] = f32x4{0.f, 0.f, 0.f, 0.f};
  #pragma unroll
  for (int kk = 0; kk < 8; kk++) {
    s16x8 a = readA(A, lo, kk, hi);
    #pragma unroll
    for (int ct = 0; ct < 12; ct++) {
      s16x8 b = readB(bt_in, wave * 192 + ct * 16 + lo, kk, hi);
      acc[ct] = mfma16(a, b, acc[ct]);
    }
  }
  #pragma unroll
  for (int ct = 0; ct < 12; ct++) {
    int col = wave * 192 + ct * 16 + lo;
    #pragma unroll
    for (int r = 0; r < 4; r++) C[(hi * 4 + r) * 768 + col] = acc[ct][r];
  }
  __syncthreads();
  #pragma unroll
  for (int mm = 0; mm < 4; mm++) {
    int m = wave * 4 + mm;
    float x[12]; float s = 0.f, q = 0.f;
    #pragma unroll
    for (int i = 0; i < 12; i++) {
      x[i] = C[m * 768 + lane + 64 * i];
      s += x[i]; q += x[i] * x[i];
    }
    s = wredsum(s); q = wredsum(q);
    float mean = s * (1.0f / 768.0f);
    float var = q * (1.0f / 768.0f) - mean * mean;
    float rstd = rsqrtf(var + LN_EPS);
    int gr = r0 + m;
    #pragma unroll
    for (int i = 0; i < 12; i++) {
      int c = lane + 64 * i;
      float y = g_pre[c] * (x[i] - mean) * rstd + b_pre[c];
      if (c < 256)      Z [gr * 256 + c]         = fast_sigmoid(y);
      else if (c < 512) HG[gr * 256 + (c - 256)] = fast_sigmoid(y);
      else              XT[gr * 256 + (c - 512)] = y;
    }
  }
}

// ---------------- K2: SRU scan over T ----------------
__global__ __launch_bounds__(256) void k_scan(
    const float* hidden, const float* Z, const float* XT,
    float* SS, float* outFinalH) {
  int tid = blockIdx.x * 256 + threadIdx.x;  // 0..8191 == b*256+d
  float h = hidden[tid];
  for (int t0 = 0; t0 < 128; t0 += 8) {
    float zc[8], xc[8];
    #pragma unroll
    for (int j = 0; j < 8; j++) {
      zc[j] = Z [(t0 + j) * 8192 + tid];
      xc[j] = XT[(t0 + j) * 8192 + tid];
    }
    #pragma unroll
    for (int j = 0; j < 8; j++) {
      h = (1.0f - zc[j]) * h + zc[j] * xc[j];
      SS[(t0 + j) * 8192 + tid] = h;
    }
  }
  outFinalH[tid] = h;
}

// ---------------- K3: q = LN(ss @ W_q) ----------------
__global__ __launch_bounds__(256) void k_qproj(
    const float* SS, const unsigned short* bt_q,
    const float* g_q, const float* b_q, float* Q) {
  __shared__ __align__(16) unsigned short A[16 * 256];
  __shared__ float C[16 * 256];
  int tid = threadIdx.x, lane = tid & 63, wave = tid >> 6;
  int hi = lane >> 4, lo = lane & 15;
  int r0 = blockIdx.x * 16;
  stage_rows(A, SS + (size_t)r0 * 256, 16, tid, 256);
  __syncthreads();
  f32x4 acc[4];
  #pragma unroll
  for (int ct = 0; ct < 4; ct++) acc[ct] = f32x4{0.f, 0.f, 0.f, 0.f};
  #pragma unroll
  for (int kk = 0; kk < 8; kk++) {
    s16x8 a = readA(A, lo, kk, hi);
    #pragma unroll
    for (int ct = 0; ct < 4; ct++) {
      s16x8 b = readB(bt_q, wave * 64 + ct * 16 + lo, kk, hi);
      acc[ct] = mfma16(a, b, acc[ct]);
    }
  }
  #pragma unroll
  for (int ct = 0; ct < 4; ct++) {
    int col = wave * 64 + ct * 16 + lo;
    #pragma unroll
    for (int r = 0; r < 4; r++) C[(hi * 4 + r) * 256 + col] = acc[ct][r];
  }
  __syncthreads();
  #pragma unroll
  for (int mm = 0; mm < 4; mm++) {
    int m = wave * 4 + mm;
    float x[4]; float s = 0.f, q = 0.f;
    #pragma unroll
    for (int i = 0; i < 4; i++) {
      x[i] = C[m * 256 + lane + 64 * i];
      s += x[i]; q += x[i] * x[i];
    }
    s = wredsum(s); q = wredsum(q);
    float mean = s * (1.0f / 256.0f);
    float var = q * (1.0f / 256.0f) - mean * mean;
    float rstd = rsqrtf(var + LN_EPS);
    int gr = r0 + m;
    #pragma unroll
    for (int i = 0; i < 4; i++) {
      int c = lane + 64 * i;
      Q[gr * 256 + c] = g_q[c] * (x[i] - mean) * rstd + b_q[c];
    }
  }
}

// ---------------- K4: fused pctx GEMM + LN + MLP-attention ----------------
// LN fold: sum_s p_s * (g*(x_s-m_s)*r_s + b) = g*(sum_s a_s*x_s - beta) + b
// with a_s = p_s*r_s, beta = sum_s p_s*m_s*r_s. Weighted sum uses RAW P tile.
__global__ __launch_bounds__(512) void k_attn(
    const float* enc, const unsigned short* bt_enc, const float* Q,
    const float* g_enc, const float* b_enc, const float* v_att,
    float* AOUT, float* attnOut) {
  // AP: swizzled A staging during GEMM, then linear bf16 raw-P tile (rows<100).
  // Rows 100..111 (bytes 51200..57344) are dead after GEMM -> overlay scratch.
  __shared__ __align__(16) unsigned short AP[112 * 256];  // 57344 B
  __shared__ float scores[112];   // scores, then alpha[s] = p_s * rstd_s
  __shared__ float beta_s;
  __shared__ float qs[256], gs[256], bs[256], vs[256];
  float*  means = (float*) ((char*)AP + 55296);   // [112]
  float*  rstds = (float*) ((char*)AP + 55744);   // [112]
  f32x2*  part  = (f32x2*) ((char*)AP + 51200);   // [4][128] f32x2 partials
  int n = blockIdx.x;
  int tid = threadIdx.x, lane = tid & 63, wave = tid >> 6;
  int hi = lane >> 4, lo = lane & 15;
  if (tid < 256) {
    qs[tid] = Q[n * 256 + tid];
    gs[tid] = g_enc[tid]; bs[tid] = b_enc[tid]; vs[tid] = v_att[tid];
  }
  stage_rows(AP, enc + (size_t)n * 25600, 100, tid, 512);
  __syncthreads();
  f32x4 acc[7][2];
  #pragma unroll
  for (int mt = 0; mt < 7; mt++) {
    acc[mt][0] = f32x4{0.f, 0.f, 0.f, 0.f};
    acc[mt][1] = f32x4{0.f, 0.f, 0.f, 0.f};
  }
  #pragma unroll
  for (int kk = 0; kk < 8; kk++) {
    s16x8 b0 = readB(bt_enc, wave * 32 + lo, kk, hi);
    s16x8 b1 = readB(bt_enc, wave * 32 + 16 + lo, kk, hi);
    #pragma unroll
    for (int mt = 0; mt < 7; mt++) {
      s16x8 a = readA(AP, mt * 16 + lo, kk, hi);
      acc[mt][0] = mfma16(a, b0, acc[mt][0]);
      acc[mt][1] = mfma16(a, b1, acc[mt][1]);
    }
  }
  __syncthreads();   // A reads done; AP becomes the raw P tile (linear layout)
  #pragma unroll
  for (int mt = 0; mt < 7; mt++) {
    #pragma unroll
    for (int ct = 0; ct < 2; ct++) {
      int col = wave * 32 + ct * 16 + lo;
      #pragma unroll
      for (int r = 0; r < 4; r++) {
        int row = mt * 16 + hi * 4 + r;
        if (row < 100) AP[row * 256 + col] = f2bf(acc[mt][ct][r]);
      }
    }
  }
  __syncthreads();
  // per-row LN stats + scores (no write-back of normalized values)
  {
    int ca = lane * 2;                 // cols ca, ca+1, ca+128, ca+129
    float g0 = gs[ca], g1 = gs[ca + 1], g2 = gs[ca + 128], g3 = gs[ca + 129];
    float b0 = bs[ca], b1 = bs[ca + 1], b2 = bs[ca + 128], b3 = bs[ca + 129];
    float v0 = vs[ca], v1 = vs[ca + 1], v2 = vs[ca + 128], v3 = vs[ca + 129];
    float q0 = qs[ca], q1 = qs[ca + 1], q2 = qs[ca + 128], q3 = qs[ca + 129];
    for (int m = wave; m < 100; m += 8) {
      const unsigned* Prow = (const unsigned*)(AP + m * 256);
      unsigned u01 = Prow[lane], u23 = Prow[lane + 64];
      float x0 = bflo(u01), x1 = bfhi(u01), x2 = bflo(u23), x3 = bfhi(u23);
      float s = (x0 + x1) + (x2 + x3);
      float q = fmaf(x0, x0, fmaf(x1, x1, fmaf(x2, x2, x3 * x3)));
      s = wredsum(s); q = wredsum(q);
      float mean = s * (1.0f / 256.0f);
      float var = q * (1.0f / 256.0f) - mean * mean;
      float rstd = rsqrtf(var + LN_EPS);
      float sc;
      sc  = v0 * fast_tanh(q0 + fmaf(g0, (x0 - mean) * rstd, b0));
      sc += v1 * fast_tanh(q1 + fmaf(g1, (x1 - mean) * rstd, b1));
      sc += v2 * fast_tanh(q2 + fmaf(g2, (x2 - mean) * rstd, b2));
      sc += v3 * fast_tanh(q3 + fmaf(g3, (x3 - mean) * rstd, b3));
      sc = wredsum(sc);
      if (lane == 0) { scores[m] = sc; means[m] = mean; rstds[m] = rstd; }
    }
  }
  __syncthreads();
  if (wave == 0) {
    float s1 = (lane < 100) ? scores[lane] : -INFINITY;
    float s2 = (lane + 64 < 100) ? scores[lane + 64] : -INFINITY;
    float mx = fmaxf(s1, s2);
    #pragma unroll
    for (int m = 32; m >= 1; m >>= 1) mx = fmaxf(mx, __shfl_xor(mx, m));
    float e1 = (lane < 100) ? __expf(s1 - mx) : 0.f;
    float e2 = (lane + 64 < 100) ? __expf(s2 - mx) : 0.f;
    float sm = wredsum(e1 + e2);
    float inv = __builtin_amdgcn_rcpf(sm);
    float p1 = e1 * inv, p2 = e2 * inv;
    float r1 = (lane < 100) ? rstds[lane] : 0.f;
    float m1 = (lane < 100) ? means[lane] : 0.f;
    float r2 = (lane + 64 < 100) ? rstds[lane + 64] : 0.f;
    float m2 = (lane + 64 < 100) ? means[lane + 64] : 0.f;
    scores[lane] = p1 * r1;                       // alpha
    if (lane + 64 < 112) scores[lane + 64] = p2 * r2;
    float bp = wredsum(fmaf(p1 * r1, m1, p2 * r2 * m2));
    if (lane == 0) beta_s = bp;
    if (lane < 100) attnOut[(size_t)n * 100 + lane] = p1;
    if (lane + 64 < 100) attnOut[(size_t)n * 100 + lane + 64] = p2;
  }
  __syncthreads();
  // weighted sum over raw P: 4-way split over s, col-pairs, all 512 threads
  {
    int cp = tid & 127, h = tid >> 7;       // h = 0..3, s in [h*25, h*25+25)
    float a0 = 0.f, a1 = 0.f;
    #pragma unroll 5
    for (int s = h * 25; s < h * 25 + 25; s++) {
      unsigned u = *(const unsigned*)(AP + s * 256 + cp * 2);
      float al = scores[s];
      a0 = fmaf(al, bflo(u), a0);
      a1 = fmaf(al, bfhi(u), a1);
    }
    part[h * 128 + cp] = f32x2{a0, a1};
  }
  __syncthreads();
  if (tid < 256) {
    const float* pf = (const float*)part;
    int idx = (tid >> 1) * 2 + (tid & 1);
    float S1 = pf[idx] + pf[256 + idx] + pf[512 + idx] + pf[768 + idx];
    float y = fmaf(gs[tid], S1 - beta_s, bs[tid]);
    AOUT[(size_t)n * 256 + tid] = y * 0.0625f;  // / sqrt(256)
  }
}

// ---------------- K5: out = highway(tanh(LN(ss@W_hid)+LN(aout@W_ctx))) ----------------
__global__ __launch_bounds__(256) void k_out(
    const float* SS, const float* AOUT,
    const unsigned short* bt_hid, const unsigned short* bt_ctx,
    const float* g_h, const float* b_h, const float* g_c, const float* b_c,
    const float* HG, const float* prev, float* out) {
  __shared__ __align__(16) unsigned short A1[16 * 256];
  __shared__ __align__(16) unsigned short A2[16 * 256];
  __shared__ float C1[16 * 256];
  __shared__ float C2[16 * 256];
  int tid = threadIdx.x, lane = tid & 63, wave = tid >> 6;
  int hi = lane >> 4, lo = lane & 15;
  int r0 = blockIdx.x * 16;
  stage_rows(A1, SS + (size_t)r0 * 256, 16, tid, 256);
  stage_rows(A2, AOUT + (size_t)r0 * 256, 16, tid, 256);
  __syncthreads();
  f32x4 acc1[4], acc2[4];
  #pragma unroll
  for (int ct = 0; ct < 4; ct++) {
    acc1[ct] = f32x4{0.f, 0.f, 0.f, 0.f};
    acc2[ct] = f32x4{0.f, 0.f, 0.f, 0.f};
  }
  #pragma unroll
  for (int kk = 0; kk < 8; kk++) {
    s16x8 a1 = readA(A1, lo, kk, hi);
    s16x8 a2 = readA(A2, lo, kk, hi);
    #pragma unroll
    for (int ct = 0; ct < 4; ct++) {
      int col = wave * 64 + ct * 16 + lo;
      s16x8 b1 = readB(bt_hid, col, kk, hi);
      s16x8 b2 = readB(bt_ctx, col, kk, hi);
      acc1[ct] = mfma16(a1, b1, acc1[ct]);
      acc2[ct] = mfma16(a2, b2, acc2[ct]);
    }
  }
  #pragma unroll
  for (int ct = 0; ct < 4; ct++) {
    int col = wave * 64 + ct * 16 + lo;
    #pragma unroll
    for (int r = 0; r < 4; r++) {
      C1[(hi * 4 + r) * 256 + col] = acc1[ct][r];
      C2[(hi * 4 + r) * 256 + col] = acc2[ct][r];
    }
  }
  __syncthreads();
  #pragma unroll
  for (int mm = 0; mm < 4; mm++) {
    int m = wave * 4 + mm;
    float x1[4], x2[4];
    float s1 = 0.f, q1 = 0.f, s2 = 0.f, q2 = 0.f;
    #pragma unroll
    for (int i = 0; i < 4; i++) {
      x1[i] = C1[m * 256 + lane + 64 * i];
      x2[i] = C2[m * 256 + lane + 64 * i];
      s1 += x1[i]; q1 += x1[i] * x1[i];
      s2 += x2[i]; q2 += x2[i] * x2[i];
    }
    s1 = wredsum(s1); q1 = wredsum(q1);
    s2 = wredsum(s2); q2 = wredsum(q2);
    float mean1 = s1 * (1.0f / 256.0f), var1 = q1 * (1.0f / 256.0f) - mean1 * mean1;
    float mean2 = s2 * (1.0f / 256.0f), var2 = q2 * (1.0f / 256.0f) - mean2 * mean2;
    float rstd1 = rsqrtf(var1 + LN_EPS), rstd2 = rsqrtf(var2 + LN_EPS);
    int gr = r0 + m;
    #pragma unroll
    for (int i = 0; i < 4; i++) {
      int c = lane + 64 * i;
      float y1 = g_h[c] * (x1[i] - mean1) * rstd1 + b_h[c];
      float y2 = g_c[c] * (x2[i] - mean2) * rstd2 + b_c[c];
      float y = fast_tanh(y1 + y2);
      float g = HG[gr * 256 + c];
      float pv = prev[gr * 256 + c];
      out[gr * 256 + c] = (1.0f - g) * y + g * pv;
    }
  }
}

extern "C" void kernel_launch(void* const* d_in, const int* in_sizes, int n_in,
                              void* d_out, int out_size, void* d_ws, size_t ws_size,
                              hipStream_t stream) {
  const float* prev   = (const float*)d_in[0];
  const float* hidden = (const float*)d_in[1];
  const float* enc    = (const float*)d_in[2];
  const float* W_in   = (const float*)d_in[3];
  const float* W_hid  = (const float*)d_in[4];
  const float* W_ctx  = (const float*)d_in[5];
  const float* W_enc  = (const float*)d_in[6];
  const float* W_q    = (const float*)d_in[7];
  const float* v_att  = (const float*)d_in[8];
  const float* g_pre  = (const float*)d_in[9];
  const float* b_pre  = (const float*)d_in[10];
  const float* g_enc  = (const float*)d_in[11];
  const float* b_enc  = (const float*)d_in[12];
  const float* g_h    = (const float*)d_in[13];
  const float* b_h    = (const float*)d_in[14];
  const float* g_c    = (const float*)d_in[15];
  const float* b_c    = (const float*)d_in[16];
  const float* g_q    = (const float*)d_in[17];
  const float* b_q    = (const float*)d_in[18];

  char* ws = (char*)d_ws;
  unsigned short* BT_IN  = (unsigned short*)(ws + 0);        // 768x256 bf16
  unsigned short* BT_Q   = (unsigned short*)(ws + 393216);   // 256x256 bf16 (transposed)
  unsigned short* BT_HID = (unsigned short*)(ws + 524288);
  unsigned short* BT_CTX = (unsigned short*)(ws + 655360);
  unsigned short* BT_ENC = (unsigned short*)(ws + 786432);
  float* Z    = (float*)(ws + 917504);    // [4096][256]
  float* HG   = (float*)(ws + 5111808);
  float* XT   = (float*)(ws + 9306112);
  float* SS   = (float*)(ws + 13500416);
  float* Q    = (float*)(ws + 17694720);
  float* AOUT = (float*)(ws + 21889024);

  float* out    = (float*)d_out;          // [4096][256]
  float* finalH = out + 1048576;          // [32][256]
  float* attnO  = out + 1056768;          // [4096][100]

  k_convw <<<1792, 256, 0, stream>>>(W_in, W_q, W_hid, W_ctx, W_enc,
                                     BT_IN, BT_Q, BT_HID, BT_CTX, BT_ENC);
  k_preact<<<256, 256, 0, stream>>>(prev, BT_IN, g_pre, b_pre, Z, HG, XT);
  k_scan  <<<32, 256, 0, stream>>>(hidden, Z, XT, SS, finalH);
  k_qproj <<<256, 256, 0, stream>>>(SS, BT_Q, g_q, b_q, Q);
  k_attn  <<<4096, 512, 0, stream>>>(enc, BT_ENC, Q, g_enc, b_enc, v_att, AOUT, attnO);
  k_out   <<<256, 256, 0, stream>>>(SS, AOUT, BT_HID, BT_CTX,
                                    g_h, b_h, g_c, b_c, HG, prev, out);
}

// Round 3
// 289.491 us; speedup vs baseline: 1.3428x; 1.0628x over previous
//
#include <hip/hip_runtime.h>
#include <hip/hip_bf16.h>
#include <math.h>

typedef short  s16x8 __attribute__((ext_vector_type(8)));
typedef float  f32x4 __attribute__((ext_vector_type(4)));
typedef float  f32x2 __attribute__((ext_vector_type(2)));

#define LN_EPS 1e-6f

__device__ __forceinline__ unsigned short f2bf(float x) {
  union { float f; unsigned u; } v; v.f = x;
  unsigned r = v.u + 0x7FFFu + ((v.u >> 16) & 1u);  // RNE
  return (unsigned short)(r >> 16);
}
__device__ __forceinline__ float bf2f(unsigned short u) {
  union { unsigned u; float f; } v; v.u = ((unsigned)u) << 16;
  return v.f;
}
__device__ __forceinline__ float bflo(unsigned u) {
  union { unsigned u; float f; } v; v.u = u << 16; return v.f;
}
__device__ __forceinline__ float bfhi(unsigned u) {
  union { unsigned u; float f; } v; v.u = u & 0xFFFF0000u; return v.f;
}
__device__ __forceinline__ unsigned pack_bf2(float a, float b) {
  __hip_bfloat162 h = __float22bfloat162_rn(make_float2(a, b));
  unsigned u; __builtin_memcpy(&u, &h, 4); return u;
}
__device__ __forceinline__ float fast_tanh(float x) {
  float e = __expf(2.0f * x);
  return 1.0f - 2.0f * __builtin_amdgcn_rcpf(e + 1.0f);
}
__device__ __forceinline__ float fast_sigmoid(float x) {
  return __builtin_amdgcn_rcpf(1.0f + __expf(-x));
}

// ---- DPP wave(64) reductions: 4x row_ror + bcast15 + bcast31, result via readlane(63)
template <int CTRL>
__device__ __forceinline__ float dpp_add(float v) {
  union { float f; int i; } a, r;
  a.f = v;
  r.i = __builtin_amdgcn_update_dpp(0, a.i, CTRL, 0xF, 0xF, true);
  return v + r.f;
}
template <int CTRL>
__device__ __forceinline__ float dpp_max(float v) {
  union { float f; int i; } a, r;
  a.f = v;
  r.i = __builtin_amdgcn_update_dpp(a.i, a.i, CTRL, 0xF, 0xF, false);
  return fmaxf(v, r.f);
}
__device__ __forceinline__ float bcast63(float v) {
  union { float f; int i; } a, r;
  a.f = v;
  r.i = __builtin_amdgcn_readlane(a.i, 63);
  return r.f;
}
__device__ __forceinline__ float wredsum(float v) {
  v = dpp_add<0x128>(v);  // row_ror:8
  v = dpp_add<0x124>(v);  // row_ror:4
  v = dpp_add<0x122>(v);  // row_ror:2
  v = dpp_add<0x121>(v);  // row_ror:1
  v = dpp_add<0x142>(v);  // row_bcast:15
  v = dpp_add<0x143>(v);  // row_bcast:31
  return bcast63(v);
}
__device__ __forceinline__ float wredmax(float v) {
  v = dpp_max<0x128>(v);
  v = dpp_max<0x124>(v);
  v = dpp_max<0x122>(v);
  v = dpp_max<0x121>(v);
  v = dpp_max<0x142>(v);
  v = dpp_max<0x143>(v);
  return bcast63(v);
}

__device__ __forceinline__ f32x4 mfma16(s16x8 a, s16x8 b, f32x4 c) {
  return __builtin_amdgcn_mfma_f32_16x16x32_bf16(a, b, c, 0, 0, 0);
}

// stage rows x 256 f32 -> bf16 into XOR-swizzled LDS ([row][k], byte ^= (row&7)<<4)
__device__ __forceinline__ void stage_rows(unsigned short* A, const float* src,
                                           int rows, int tid, int nthreads) {
  char* Ab = (char*)A;
  int nquads = rows * 64;
  #pragma unroll 4
  for (int p = tid; p < nquads; p += nthreads) {
    int row = p >> 6, kq = p & 63;
    f32x4 v = *(const f32x4*)(src + row * 256 + kq * 4);
    unsigned u0 = pack_bf2(v.x, v.y);
    unsigned u1 = pack_bf2(v.z, v.w);
    int byte = row * 512 + ((kq * 8) ^ ((row & 7) << 4));
    *(uint2*)(Ab + byte) = uint2{u0, u1};
  }
}

// A-frag: lane holds A[row][kk*32 + 8*hi + j], j=0..7
__device__ __forceinline__ s16x8 readA(const unsigned short* A, int row, int kk, int hi) {
  const char* Ab = (const char*)A;
  int byte = row * 512 + (((kk * 64) + hi * 16) ^ ((row & 7) << 4));
  return *(const s16x8*)(Ab + byte);
}
// B-frag from transposed bf16 weights Bt[N][256]: lane holds B[kk*32+8*hi+j][col]
__device__ __forceinline__ s16x8 readB(const unsigned short* Bt, int col, int kk, int hi) {
  return *(const s16x8*)(Bt + col * 256 + kk * 32 + hi * 8);
}

// ---------------- K0: weight convert + transpose (coalesced 32x32 LDS tiles) ----------------
__global__ __launch_bounds__(256) void k_convw(
    const float* Win, const float* Wq, const float* Whid, const float* Wctx, const float* Wenc,
    unsigned short* bt_in, unsigned short* bt_q, unsigned short* bt_hid,
    unsigned short* bt_ctx, unsigned short* bt_enc) {
  __shared__ unsigned short tile[32][34];
  int b = blockIdx.x;
  const float* src; unsigned short* dst; int N, tk, tn;
  if (b < 192) { src = Win; dst = bt_in; N = 768; tk = b & 7; tn = b >> 3; }
  else {
    int bb = b - 192; int m = bb >> 6; int r = bb & 63;
    tk = r & 7; tn = r >> 3; N = 256;
    src = (m == 0) ? Wq : (m == 1) ? Whid : (m == 2) ? Wctx : Wenc;
    dst = (m == 0) ? bt_q : (m == 1) ? bt_hid : (m == 2) ? bt_ctx : bt_enc;
  }
  int k0 = tk * 32, n0 = tn * 32;
  {
    int i = threadIdx.x >> 3, j4 = (threadIdx.x & 7) * 4;
    f32x4 v = *(const f32x4*)(src + (size_t)(k0 + i) * N + n0 + j4);
    *(unsigned*)((char*)&tile[i][j4])     = pack_bf2(v.x, v.y);
    *(unsigned*)((char*)&tile[i][j4 + 2]) = pack_bf2(v.z, v.w);
  }
  __syncthreads();
  {
    int j = threadIdx.x >> 3, i4 = (threadIdx.x & 7) * 4;
    unsigned lo = (unsigned)tile[i4 + 0][j] | ((unsigned)tile[i4 + 1][j] << 16);
    unsigned hi = (unsigned)tile[i4 + 2][j] | ((unsigned)tile[i4 + 3][j] << 16);
    *(uint2*)(dst + (size_t)(n0 + j) * 256 + k0 + i4) = uint2{lo, hi};
  }
}

// ---------------- K1: preact = LN(prev @ W_in) -> z,hg,xt ----------------
__global__ __launch_bounds__(256) void k_preact(
    const float* prev, const unsigned short* bt_in,
    const float* g_pre, const float* b_pre,
    float* Z, float* HG, float* XT) {
  __shared__ __align__(16) unsigned short A[16 * 256];
  __shared__ float C[16 * 768];
  int tid = threadIdx.x, lane = tid & 63, wave = tid >> 6;
  int hi = lane >> 4, lo = lane & 15;
  int r0 = blockIdx.x * 16;
  stage_rows(A, prev + (size_t)r0 * 256, 16, tid, 256);
  __syncthreads();
  f32x4 acc[12];
  #pragma unroll
  for (int ct = 0; ct < 12; ct++) acc[ct] = f32x4{0.f, 0.f, 0.f, 0.f};
  #pragma unroll
  for (int kk = 0; kk < 8; kk++) {
    s16x8 a = readA(A, lo, kk, hi);
    #pragma unroll
    for (int ct = 0; ct < 12; ct++) {
      s16x8 b = readB(bt_in, wave * 192 + ct * 16 + lo, kk, hi);
      acc[ct] = mfma16(a, b, acc[ct]);
    }
  }
  #pragma unroll
  for (int ct = 0; ct < 12; ct++) {
    int col = wave * 192 + ct * 16 + lo;
    #pragma unroll
    for (int r = 0; r < 4; r++) C[(hi * 4 + r) * 768 + col] = acc[ct][r];
  }
  __syncthreads();
  #pragma unroll
  for (int mm = 0; mm < 4; mm++) {
    int m = wave * 4 + mm;
    float x[12]; float s = 0.f, q = 0.f;
    #pragma unroll
    for (int i = 0; i < 12; i++) {
      x[i] = C[m * 768 + lane + 64 * i];
      s += x[i]; q += x[i] * x[i];
    }
    s = wredsum(s); q = wredsum(q);
    float mean = s * (1.0f / 768.0f);
    float var = q * (1.0f / 768.0f) - mean * mean;
    float rstd = rsqrtf(var + LN_EPS);
    int gr = r0 + m;
    #pragma unroll
    for (int i = 0; i < 12; i++) {
      int c = lane + 64 * i;
      float y = g_pre[c] * (x[i] - mean) * rstd + b_pre[c];
      if (c < 256)      Z [gr * 256 + c]         = fast_sigmoid(y);
      else if (c < 512) HG[gr * 256 + (c - 256)] = fast_sigmoid(y);
      else              XT[gr * 256 + (c - 512)] = y;
    }
  }
}

// ---------------- K2: SRU scan over T ----------------
__global__ __launch_bounds__(256) void k_scan(
    const float* hidden, const float* Z, const float* XT,
    float* SS, float* outFinalH) {
  int tid = blockIdx.x * 256 + threadIdx.x;  // 0..8191 == b*256+d
  float h = hidden[tid];
  for (int t0 = 0; t0 < 128; t0 += 8) {
    float zc[8], xc[8];
    #pragma unroll
    for (int j = 0; j < 8; j++) {
      zc[j] = Z [(t0 + j) * 8192 + tid];
      xc[j] = XT[(t0 + j) * 8192 + tid];
    }
    #pragma unroll
    for (int j = 0; j < 8; j++) {
      h = (1.0f - zc[j]) * h + zc[j] * xc[j];
      SS[(t0 + j) * 8192 + tid] = h;
    }
  }
  outFinalH[tid] = h;
}

// ---------------- K3: q = LN(ss @ W_q) ----------------
__global__ __launch_bounds__(256) void k_qproj(
    const float* SS, const unsigned short* bt_q,
    const float* g_q, const float* b_q, float* Q) {
  __shared__ __align__(16) unsigned short A[16 * 256];
  __shared__ float C[16 * 256];
  int tid = threadIdx.x, lane = tid & 63, wave = tid >> 6;
  int hi = lane >> 4, lo = lane & 15;
  int r0 = blockIdx.x * 16;
  stage_rows(A, SS + (size_t)r0 * 256, 16, tid, 256);
  __syncthreads();
  f32x4 acc[4];
  #pragma unroll
  for (int ct = 0; ct < 4; ct++) acc[ct] = f32x4{0.f, 0.f, 0.f, 0.f};
  #pragma unroll
  for (int kk = 0; kk < 8; kk++) {
    s16x8 a = readA(A, lo, kk, hi);
    #pragma unroll
    for (int ct = 0; ct < 4; ct++) {
      s16x8 b = readB(bt_q, wave * 64 + ct * 16 + lo, kk, hi);
      acc[ct] = mfma16(a, b, acc[ct]);
    }
  }
  #pragma unroll
  for (int ct = 0; ct < 4; ct++) {
    int col = wave * 64 + ct * 16 + lo;
    #pragma unroll
    for (int r = 0; r < 4; r++) C[(hi * 4 + r) * 256 + col] = acc[ct][r];
  }
  __syncthreads();
  #pragma unroll
  for (int mm = 0; mm < 4; mm++) {
    int m = wave * 4 + mm;
    float x[4]; float s = 0.f, q = 0.f;
    #pragma unroll
    for (int i = 0; i < 4; i++) {
      x[i] = C[m * 256 + lane + 64 * i];
      s += x[i]; q += x[i] * x[i];
    }
    s = wredsum(s); q = wredsum(q);
    float mean = s * (1.0f / 256.0f);
    float var = q * (1.0f / 256.0f) - mean * mean;
    float rstd = rsqrtf(var + LN_EPS);
    int gr = r0 + m;
    #pragma unroll
    for (int i = 0; i < 4; i++) {
      int c = lane + 64 * i;
      Q[gr * 256 + c] = g_q[c] * (x[i] - mean) * rstd + b_q[c];
    }
  }
}

// ---------------- K4: fused pctx GEMM + LN + MLP-attention ----------------
// LN fold: sum_s p_s * (g*(x_s-m_s)*r_s + b) = g*(sum_s a_s*x_s - beta) + b
__global__ __launch_bounds__(512, 6) void k_attn(
    const float* enc, const unsigned short* bt_enc, const float* Q,
    const float* g_enc, const float* b_enc, const float* v_att,
    float* AOUT, float* attnOut) {
  // AP: swizzled A staging during GEMM, then linear bf16 raw-P tile. 100 rows only.
  __shared__ __align__(16) unsigned short AP[100 * 256];  // 51200 B
  __shared__ __align__(16) float alpha[112];  // scores, then alpha[s]=p_s*rstd_s
  __shared__ __align__(16) float stat[256];   // means[0..112) rstds[112..224); wsum partials[0..256)
  __shared__ float beta_s;
  int n = blockIdx.x;
  int tid = threadIdx.x, lane = tid & 63, wave = tid >> 6;
  int hi = lane >> 4, lo = lane & 15;
  stage_rows(AP, enc + (size_t)n * 25600, 100, tid, 512);
  __syncthreads();
  f32x4 acc[7][2];
  #pragma unroll
  for (int mt = 0; mt < 7; mt++) {
    acc[mt][0] = f32x4{0.f, 0.f, 0.f, 0.f};
    acc[mt][1] = f32x4{0.f, 0.f, 0.f, 0.f};
  }
  #pragma unroll
  for (int kk = 0; kk < 8; kk++) {
    s16x8 b0 = readB(bt_enc, wave * 32 + lo, kk, hi);
    s16x8 b1 = readB(bt_enc, wave * 32 + 16 + lo, kk, hi);
    #pragma unroll
    for (int mt = 0; mt < 7; mt++) {
      int ar = mt * 16 + lo;
      ar = ar > 99 ? 99 : ar;   // mt=6 ragged tile: rows >=100 read row 99, acc discarded
      s16x8 a = readA(AP, ar, kk, hi);
      acc[mt][0] = mfma16(a, b0, acc[mt][0]);
      acc[mt][1] = mfma16(a, b1, acc[mt][1]);
    }
  }
  __syncthreads();   // A reads done; AP becomes the raw P tile (linear layout)
  #pragma unroll
  for (int mt = 0; mt < 7; mt++) {
    int col = wave * 32 + lo;
    #pragma unroll
    for (int r = 0; r < 4; r++) {
      int row = mt * 16 + hi * 4 + r;
      if (row < 100) {
        unsigned u = pack_bf2(acc[mt][0][r], acc[mt][1][r]);
        AP[row * 256 + col]      = (unsigned short)u;
        AP[row * 256 + col + 16] = (unsigned short)(u >> 16);
      }
    }
  }
  __syncthreads();
  // per-row LN stats + scores (params loaded AFTER acc dies -> low peak VGPR)
  {
    int ca = lane * 2;
    f32x2 gA = *(const f32x2*)(g_enc + ca), gB = *(const f32x2*)(g_enc + ca + 128);
    f32x2 bA = *(const f32x2*)(b_enc + ca), bB = *(const f32x2*)(b_enc + ca + 128);
    f32x2 vA = *(const f32x2*)(v_att + ca), vB = *(const f32x2*)(v_att + ca + 128);
    f32x2 qA = *(const f32x2*)(Q + (size_t)n * 256 + ca);
    f32x2 qB = *(const f32x2*)(Q + (size_t)n * 256 + ca + 128);
    #pragma unroll 2
    for (int m = wave; m < 100; m += 8) {
      const unsigned* Prow = (const unsigned*)(AP + m * 256);
      unsigned u01 = Prow[lane], u23 = Prow[lane + 64];
      float x0 = bflo(u01), x1 = bfhi(u01), x2 = bflo(u23), x3 = bfhi(u23);
      float s = (x0 + x1) + (x2 + x3);
      float q = fmaf(x0, x0, fmaf(x1, x1, fmaf(x2, x2, x3 * x3)));
      s = wredsum(s); q = wredsum(q);
      float mean = s * (1.0f / 256.0f);
      float var = q * (1.0f / 256.0f) - mean * mean;
      float rstd = rsqrtf(var + LN_EPS);
      float sc;
      sc  = vA.x * fast_tanh(qA.x + fmaf(gA.x, (x0 - mean) * rstd, bA.x));
      sc += vA.y * fast_tanh(qA.y + fmaf(gA.y, (x1 - mean) * rstd, bA.y));
      sc += vB.x * fast_tanh(qB.x + fmaf(gB.x, (x2 - mean) * rstd, bB.x));
      sc += vB.y * fast_tanh(qB.y + fmaf(gB.y, (x3 - mean) * rstd, bB.y));
      sc = wredsum(sc);
      if (lane == 0) { alpha[m] = sc; stat[m] = mean; stat[112 + m] = rstd; }
    }
  }
  __syncthreads();
  if (wave == 0) {
    float s1 = (lane < 100) ? alpha[lane] : -INFINITY;
    float s2 = (lane < 36)  ? alpha[lane + 64] : -INFINITY;
    float mx = wredmax(fmaxf(s1, s2));
    float e1 = (lane < 100) ? __expf(s1 - mx) : 0.f;
    float e2 = (lane < 36)  ? __expf(s2 - mx) : 0.f;
    float sm = wredsum(e1 + e2);
    float inv = __builtin_amdgcn_rcpf(sm);
    float p1 = e1 * inv, p2 = e2 * inv;
    float r1 = (lane < 100) ? stat[112 + lane] : 0.f;
    float m1 = (lane < 100) ? stat[lane] : 0.f;
    float r2 = (lane < 36)  ? stat[112 + lane + 64] : 0.f;
    float m2 = (lane < 36)  ? stat[lane + 64] : 0.f;
    float a1 = p1 * r1, a2 = p2 * r2;
    alpha[lane] = a1;
    if (lane < 48) alpha[lane + 64] = a2;
    float bp = wredsum(fmaf(a1, m1, a2 * m2));
    if (lane == 0) beta_s = bp;
    if (lane < 100) attnOut[(size_t)n * 100 + lane] = p1;
    if (lane < 36)  attnOut[(size_t)n * 100 + lane + 64] = p2;
  }
  __syncthreads();
  // weighted sum over raw P: 256 cols x 2 s-halves; partials overlay stat[]
  {
    int c = tid & 255, h = tid >> 8;
    float a = 0.f;
    #pragma unroll 5
    for (int s = h * 50; s < h * 50 + 50; s += 2) {
      f32x2 al = *(const f32x2*)(alpha + s);
      a = fmaf(al.x, bf2f(AP[s * 256 + c]), a);
      a = fmaf(al.y, bf2f(AP[(s + 1) * 256 + c]), a);
    }
    if (h == 1) stat[c] = a;
    __syncthreads();
    if (h == 0) {
      float S1 = a + stat[c];
      float y = fmaf(g_enc[c], S1 - beta_s, b_enc[c]);
      AOUT[(size_t)n * 256 + c] = y * 0.0625f;  // / sqrt(256)
    }
  }
}

// ---------------- K5: out = highway(tanh(LN(ss@W_hid)+LN(aout@W_ctx))) ----------------
__global__ __launch_bounds__(256) void k_out(
    const float* SS, const float* AOUT,
    const unsigned short* bt_hid, const unsigned short* bt_ctx,
    const float* g_h, const float* b_h, const float* g_c, const float* b_c,
    const float* HG, const float* prev, float* out) {
  __shared__ __align__(16) unsigned short A1[16 * 256];
  __shared__ __align__(16) unsigned short A2[16 * 256];
  __shared__ float C1[16 * 256];
  __shared__ float C2[16 * 256];
  int tid = threadIdx.x, lane = tid & 63, wave = tid >> 6;
  int hi = lane >> 4, lo = lane & 15;
  int r0 = blockIdx.x * 16;
  stage_rows(A1, SS + (size_t)r0 * 256, 16, tid, 256);
  stage_rows(A2, AOUT + (size_t)r0 * 256, 16, tid, 256);
  __syncthreads();
  f32x4 acc1[4], acc2[4];
  #pragma unroll
  for (int ct = 0; ct < 4; ct++) {
    acc1[ct] = f32x4{0.f, 0.f, 0.f, 0.f};
    acc2[ct] = f32x4{0.f, 0.f, 0.f, 0.f};
  }
  #pragma unroll
  for (int kk = 0; kk < 8; kk++) {
    s16x8 a1 = readA(A1, lo, kk, hi);
    s16x8 a2 = readA(A2, lo, kk, hi);
    #pragma unroll
    for (int ct = 0; ct < 4; ct++) {
      int col = wave * 64 + ct * 16 + lo;
      s16x8 b1 = readB(bt_hid, col, kk, hi);
      s16x8 b2 = readB(bt_ctx, col, kk, hi);
      acc1[ct] = mfma16(a1, b1, acc1[ct]);
      acc2[ct] = mfma16(a2, b2, acc2[ct]);
    }
  }
  #pragma unroll
  for (int ct = 0; ct < 4; ct++) {
    int col = wave * 64 + ct * 16 + lo;
    #pragma unroll
    for (int r = 0; r < 4; r++) {
      C1[(hi * 4 + r) * 256 + col] = acc1[ct][r];
      C2[(hi * 4 + r) * 256 + col] = acc2[ct][r];
    }
  }
  __syncthreads();
  #pragma unroll
  for (int mm = 0; mm < 4; mm++) {
    int m = wave * 4 + mm;
    float x1[4], x2[4];
    float s1 = 0.f, q1 = 0.f, s2 = 0.f, q2 = 0.f;
    #pragma unroll
    for (int i = 0; i < 4; i++) {
      x1[i] = C1[m * 256 + lane + 64 * i];
      x2[i] = C2[m * 256 + lane + 64 * i];
      s1 += x1[i]; q1 += x1[i] * x1[i];
      s2 += x2[i]; q2 += x2[i] * x2[i];
    }
    s1 = wredsum(s1); q1 = wredsum(q1);
    s2 = wredsum(s2); q2 = wredsum(q2);
    float mean1 = s1 * (1.0f / 256.0f), var1 = q1 * (1.0f / 256.0f) - mean1 * mean1;
    float mean2 = s2 * (1.0f / 256.0f), var2 = q2 * (1.0f / 256.0f) - mean2 * mean2;
    float rstd1 = rsqrtf(var1 + LN_EPS), rstd2 = rsqrtf(var2 + LN_EPS);
    int gr = r0 + m;
    #pragma unroll
    for (int i = 0; i < 4; i++) {
      int c = lane + 64 * i;
      float y1 = g_h[c] * (x1[i] - mean1) * rstd1 + b_h[c];
      float y2 = g_c[c] * (x2[i] - mean2) * rstd2 + b_c[c];
      float y = fast_tanh(y1 + y2);
      float g = HG[gr * 256 + c];
      float pv = prev[gr * 256 + c];
      out[gr * 256 + c] = (1.0f - g) * y + g * pv;
    }
  }
}

extern "C" void kernel_launch(void* const* d_in, const int* in_sizes, int n_in,
                              void* d_out, int out_size, void* d_ws, size_t ws_size,
                              hipStream_t stream) {
  const float* prev   = (const float*)d_in[0];
  const float* hidden = (const float*)d_in[1];
  const float* enc    = (const float*)d_in[2];
  const float* W_in   = (const float*)d_in[3];
  const float* W_hid  = (const float*)d_in[4];
  const float* W_ctx  = (const float*)d_in[5];
  const float* W_enc  = (const float*)d_in[6];
  const float* W_q    = (const float*)d_in[7];
  const float* v_att  = (const float*)d_in[8];
  const float* g_pre  = (const float*)d_in[9];
  const float* b_pre  = (const float*)d_in[10];
  const float* g_enc  = (const float*)d_in[11];
  const float* b_enc  = (const float*)d_in[12];
  const float* g_h    = (const float*)d_in[13];
  const float* b_h    = (const float*)d_in[14];
  const float* g_c    = (const float*)d_in[15];
  const float* b_c    = (const float*)d_in[16];
  const float* g_q    = (const float*)d_in[17];
  const float* b_q    = (const float*)d_in[18];

  char* ws = (char*)d_ws;
  unsigned short* BT_IN  = (unsigned short*)(ws + 0);        // 768x256 bf16
  unsigned short* BT_Q   = (unsigned short*)(ws + 393216);
  unsigned short* BT_HID = (unsigned short*)(ws + 524288);
  unsigned short* BT_CTX = (unsigned short*)(ws + 655360);
  unsigned short* BT_ENC = (unsigned short*)(ws + 786432);
  float* Z    = (float*)(ws + 917504);    // [4096][256]
  float* HG   = (float*)(ws + 5111808);
  float* XT   = (float*)(ws + 9306112);
  float* SS   = (float*)(ws + 13500416);
  float* Q    = (float*)(ws + 17694720);
  float* AOUT = (float*)(ws + 21889024);

  float* out    = (float*)d_out;          // [4096][256]
  float* finalH = out + 1048576;          // [32][256]
  float* attnO  = out + 1056768;          // [4096][100]

  k_convw <<<448, 256, 0, stream>>>(W_in, W_q, W_hid, W_ctx, W_enc,
                                    BT_IN, BT_Q, BT_HID, BT_CTX, BT_ENC);
  k_preact<<<256, 256, 0, stream>>>(prev, BT_IN, g_pre, b_pre, Z, HG, XT);
  k_scan  <<<32, 256, 0, stream>>>(hidden, Z, XT, SS, finalH);
  k_qproj <<<256, 256, 0, stream>>>(SS, BT_Q, g_q, b_q, Q);
  k_attn  <<<4096, 512, 0, stream>>>(enc, BT_ENC, Q, g_enc, b_enc, v_att, AOUT, attnO);
  k_out   <<<256, 256, 0, stream>>>(SS, AOUT, BT_HID, BT_CTX,
                                    g_h, b_h, g_c, b_c, HG, prev, out);
}